// Round 1
// baseline (159.046 us; speedup 1.0000x reference)
//
#include <hip/hip_runtime.h>

// Problem: B=4096, NP=512, NFFT=4096. Distance-aware exponential interpolation
// from NP pilot positions to NFFT grid points, per batch row, 2 channels (re/im).
//
// Key structural fact: left[i], w_l[i], w_r[i], w[i] depend only on i — shared
// across all B rows. Precompute {a=w_l/w, c=w_r/w, left} once (pass 1, 64 KB in
// d_ws), then pass 2 is a pure streaming kernel: 134 MB write + 17 MB read.

#define NP_MAX 512

__global__ void dai_weights_kernel(const float* __restrict__ pilot_pos,
                                   const float* __restrict__ decay_param,
                                   float4* __restrict__ wout,
                                   int NP, int Nfft) {
    int i = blockIdx.x * blockDim.x + threadIdx.x;
    if (i >= Nfft) return;

    float decay = log1pf(expf(decay_param[0]));  // softplus
    float fi = (float)i;

    // searchsorted(locext, i, side='right') where
    // locext = [0] + (pilot_pos - 1) + [Nfft-1], len NP+2.
    // Count pilots with pilot_pos[k]-1 <= i via binary search (ascending).
    int lo = 0, hi = NP;
    while (lo < hi) {
        int mid = (lo + hi) >> 1;
        if (pilot_pos[mid] - 1.0f <= fi) lo = mid + 1; else hi = mid;
    }
    int count = 1 + lo + (((float)(Nfft - 1)) <= fi ? 1 : 0);
    int left = count - 1;
    left = min(max(left, 0), NP);   // clip to [0, NP] (= len(locext)-2)
    int right = left + 1;

    // locext lookup
    float x0 = (left == 0) ? 0.0f
             : (left <= NP ? pilot_pos[left - 1] - 1.0f : (float)(Nfft - 1));
    float x1 = (right <= NP) ? pilot_pos[right - 1] - 1.0f : (float)(Nfft - 1);

    float wl = expf(-decay * fabsf(fi - x0));
    float wr = expf(-decay * fabsf(x1 - fi));
    float w = wl + wr + 1e-12f;

    float4 o;
    o.x = wl / w;
    o.y = wr / w;
    o.z = __int_as_float(left);
    o.w = 0.0f;
    wout[i] = o;
}

__global__ __launch_bounds__(256) void dai_interp_kernel(
        const float* __restrict__ LS,         // (B, NP, 2) fp32
        const float* __restrict__ pilot_pos,  // (NP,)
        const float4* __restrict__ wts,       // (Nfft,) {a, c, left, -}
        float* __restrict__ out,              // (B, Nfft, 2) fp32
        int NP, int Nfft) {
    __shared__ float2 hext[NP_MAX + 2];       // extended H row: [h0, H[b], hN]

    const int b = blockIdx.x;
    const int t = threadIdx.x;

    // Stage H[b] (NP*2 = 1024 floats = 256 float4) into LDS, one float4/thread.
    {
        const float4* row4 = (const float4*)(LS + (size_t)b * NP * 2);
        const int n4 = (NP * 2) / 4;
        for (int idx = t; idx < n4; idx += 256) {
            float4 v = row4[idx];
            hext[1 + 2 * idx] = make_float2(v.x, v.y);
            hext[2 + 2 * idx] = make_float2(v.z, v.w);
        }
    }
    __syncthreads();

    // Linear-extrapolation endpoints (one thread; negligible).
    if (t == 0) {
        float2 H0 = hext[1], H1 = hext[2];
        float2 Hl = hext[NP], Hll = hext[NP - 1];
        float loc0 = pilot_pos[0] - 1.0f;
        float loc1 = pilot_pos[1] - 1.0f;
        float locl = pilot_pos[NP - 1] - 1.0f;
        float locll = pilot_pos[NP - 2] - 1.0f;

        float sl = 1.0f / (loc1 - loc0);
        float2 h0;
        h0.x = H0.x - (H1.x - H0.x) * sl * loc0;
        h0.y = H0.y - (H1.y - H0.y) * sl * loc0;

        float sr = 1.0f / (locl - locll);
        float tr = (float)(Nfft - 1) - locl;
        float2 hN;
        hN.x = Hl.x + (Hl.x - Hll.x) * sr * tr;
        hN.y = Hl.y + (Hl.y - Hll.y) * sr * tr;

        hext[0] = h0;
        hext[NP + 1] = hN;
    }
    __syncthreads();

    // Stream Nfft/2 float4 outputs (2 interp points each), fully coalesced.
    float4* out4 = (float4*)(out + (size_t)b * Nfft * 2);
    const int npairs = Nfft >> 1;
    for (int p = t; p < npairs; p += 256) {
        float4 w0 = wts[2 * p];
        float4 w1 = wts[2 * p + 1];
        int l0 = __float_as_int(w0.z);
        int l1 = __float_as_int(w1.z);
        float2 y00 = hext[l0], y01 = hext[l0 + 1];
        float2 y10 = hext[l1], y11 = hext[l1 + 1];
        float4 o;
        o.x = w0.x * y00.x + w0.y * y01.x;
        o.y = w0.x * y00.y + w0.y * y01.y;
        o.z = w1.x * y10.x + w1.y * y11.x;
        o.w = w1.x * y10.y + w1.y * y11.y;
        out4[p] = o;
    }
}

extern "C" void kernel_launch(void* const* d_in, const int* in_sizes, int n_in,
                              void* d_out, int out_size, void* d_ws, size_t ws_size,
                              hipStream_t stream) {
    const float* LS     = (const float*)d_in[0];   // (B, NP, 2)
    const float* pilot  = (const float*)d_in[1];   // (NP,)
    const float* decayp = (const float*)d_in[2];   // (1,)
    // d_in[3] is Nfft (device int); derive shapes from sizes instead.

    const int NP   = in_sizes[1];
    const int B    = in_sizes[0] / (2 * NP);
    const int Nfft = out_size / (2 * B);

    float4* wts = (float4*)d_ws;   // Nfft * 16 B = 64 KB

    dai_weights_kernel<<<(Nfft + 255) / 256, 256, 0, stream>>>(
        pilot, decayp, wts, NP, Nfft);
    dai_interp_kernel<<<B, 256, 0, stream>>>(
        LS, pilot, wts, (float*)d_out, NP, Nfft);
}

// Round 2
// 156.508 us; speedup vs baseline: 1.0162x; 1.0162x over previous
//
#include <hip/hip_runtime.h>

// Problem: B=4096, NP=512, NFFT=4096. Distance-aware exponential interpolation.
// out[b,i,c] = (wl[i]*Hext[b,left[i],c] + wr[i]*Hext[b,left[i]+1,c]) / w[i]
// Weights/indices depend only on i -> precomputed once (pass 1).
// Pass 2 v2: compile-time shapes, ROWS rows per block, weights in registers
// (loaded once per block), double-buffered LDS staging, fully unrolled inner
// loop. Memory floor: 134 MB write + 17 MB read ~= 24 us at 6.3 TB/s.

#define NP_C    512
#define NFFT_C  4096
#define ROWS_C  4
#define THREADS 256

// ---------------- pass 1: per-i weights (shared across all rows) -----------
__global__ void dai_weights_kernel(const float* __restrict__ pilot_pos,
                                   const float* __restrict__ decay_param,
                                   float4* __restrict__ wout,
                                   int NP, int Nfft) {
    int i = blockIdx.x * blockDim.x + threadIdx.x;
    if (i >= Nfft) return;

    float decay = log1pf(expf(decay_param[0]));  // softplus
    float fi = (float)i;

    // searchsorted(locext, i, 'right')-1 where locext = [0, pilot_pos-1, Nfft-1]
    int lo = 0, hi = NP;
    while (lo < hi) {
        int mid = (lo + hi) >> 1;
        if (pilot_pos[mid] - 1.0f <= fi) lo = mid + 1; else hi = mid;
    }
    int count = 1 + lo + (((float)(Nfft - 1)) <= fi ? 1 : 0);
    int left = min(max(count - 1, 0), NP);
    int right = left + 1;

    float x0 = (left == 0) ? 0.0f
             : (left <= NP ? pilot_pos[left - 1] - 1.0f : (float)(Nfft - 1));
    float x1 = (right <= NP) ? pilot_pos[right - 1] - 1.0f : (float)(Nfft - 1);

    float wl = expf(-decay * fabsf(fi - x0));
    float wr = expf(-decay * fabsf(x1 - fi));
    float w = wl + wr + 1e-12f;

    float4 o;
    o.x = wl / w;
    o.y = wr / w;
    o.z = __int_as_float(left);
    o.w = 0.0f;
    wout[i] = o;
}

// ---------------- pass 2 (specialized): multi-row streaming ----------------
__global__ __launch_bounds__(THREADS) void dai_interp_mr(
        const float* __restrict__ LS,         // (B, NP, 2)
        const float* __restrict__ pilot_pos,  // (NP,)
        const float4* __restrict__ wts,       // (NFFT,) {a, c, left, -}
        float* __restrict__ out) {            // (B, NFFT, 2)
    constexpr int NP = NP_C, NFFT = NFFT_C, ROWS = ROWS_C;
    constexpr int PAIRS = NFFT / 2;           // 2048 float4 outputs per row
    constexpr int PPT = PAIRS / THREADS;      // 8 pairs per thread

    __shared__ float2 hext[2][NP + 2];        // double-buffered extended rows

    const int t = threadIdx.x;
    const int b0 = blockIdx.x * ROWS;

    // Weight table -> registers, once per block (64 VGPRs).
    float4 w0[PPT], w1[PPT];
#pragma unroll
    for (int j = 0; j < PPT; ++j) {
        int p = t + THREADS * j;
        w0[j] = wts[2 * p];
        w1[j] = wts[2 * p + 1];
    }

    const float loc0  = pilot_pos[0] - 1.0f;
    const float loc1  = pilot_pos[1] - 1.0f;
    const float locll = pilot_pos[NP - 2] - 1.0f;
    const float locl  = pilot_pos[NP - 1] - 1.0f;
    const float inv_l = 1.0f / (loc1 - loc0);
    const float inv_r = 1.0f / (locl - locll);
    const float tr    = (float)(NFFT - 1) - locl;

    // Stage one row into hext[buf]: 256 float4 = one per thread; thread 0
    // also computes the linear-extrapolation endpoints straight from global.
    auto stage = [&](int r, int buf) {
        const float* rowp = LS + (size_t)(b0 + r) * NP * 2;
        float4 v = ((const float4*)rowp)[t];
        float2* dst = hext[buf];
        dst[1 + 2 * t] = make_float2(v.x, v.y);
        dst[2 + 2 * t] = make_float2(v.z, v.w);
        if (t == 0) {
            float2 H0  = ((const float2*)rowp)[0];
            float2 H1  = ((const float2*)rowp)[1];
            float2 Hll = ((const float2*)rowp)[NP - 2];
            float2 Hl  = ((const float2*)rowp)[NP - 1];
            float2 h0, hN;
            h0.x = H0.x - (H1.x - H0.x) * inv_l * loc0;
            h0.y = H0.y - (H1.y - H0.y) * inv_l * loc0;
            hN.x = Hl.x + (Hl.x - Hll.x) * inv_r * tr;
            hN.y = Hl.y + (Hl.y - Hll.y) * inv_r * tr;
            dst[0] = h0;
            dst[NP + 1] = hN;
        }
    };

    stage(0, 0);
    __syncthreads();

    for (int r = 0; r < ROWS; ++r) {
        if (r + 1 < ROWS) stage(r + 1, (r + 1) & 1);

        const float2* h = hext[r & 1];
        float4* out4 = (float4*)(out + (size_t)(b0 + r) * NFFT * 2);
#pragma unroll
        for (int j = 0; j < PPT; ++j) {
            int p = t + THREADS * j;
            int l0 = __float_as_int(w0[j].z);
            int l1 = __float_as_int(w1[j].z);
            float2 y00 = h[l0], y01 = h[l0 + 1];
            float2 y10 = h[l1], y11 = h[l1 + 1];
            float4 o;
            o.x = w0[j].x * y00.x + w0[j].y * y01.x;
            o.y = w0[j].x * y00.y + w0[j].y * y01.y;
            o.z = w1[j].x * y10.x + w1[j].y * y11.x;
            o.w = w1[j].x * y10.y + w1[j].y * y11.y;
            out4[p] = o;
        }
        __syncthreads();   // staging of r+1 done AND compute of r done
    }
}

// ---------------- generic fallback (shape mismatch safety) -----------------
__global__ __launch_bounds__(256) void dai_interp_generic(
        const float* __restrict__ LS, const float* __restrict__ pilot_pos,
        const float4* __restrict__ wts, float* __restrict__ out,
        int NP, int Nfft) {
    extern __shared__ float2 hext[];
    const int b = blockIdx.x;
    const int t = threadIdx.x;
    {
        const float2* row2 = (const float2*)(LS + (size_t)b * NP * 2);
        for (int idx = t; idx < NP; idx += 256) hext[1 + idx] = row2[idx];
    }
    __syncthreads();
    if (t == 0) {
        float2 H0 = hext[1], H1 = hext[2];
        float2 Hl = hext[NP], Hll = hext[NP - 1];
        float loc0 = pilot_pos[0] - 1.0f, loc1 = pilot_pos[1] - 1.0f;
        float locl = pilot_pos[NP - 1] - 1.0f, locll = pilot_pos[NP - 2] - 1.0f;
        float sl = 1.0f / (loc1 - loc0), sr = 1.0f / (locl - locll);
        float trr = (float)(Nfft - 1) - locl;
        hext[0] = make_float2(H0.x - (H1.x - H0.x) * sl * loc0,
                              H0.y - (H1.y - H0.y) * sl * loc0);
        hext[NP + 1] = make_float2(Hl.x + (Hl.x - Hll.x) * sr * trr,
                                   Hl.y + (Hl.y - Hll.y) * sr * trr);
    }
    __syncthreads();
    float2* out2 = (float2*)(out + (size_t)b * Nfft * 2);
    for (int i = t; i < Nfft; i += 256) {
        float4 w = wts[i];
        int l = __float_as_int(w.z);
        float2 y0 = hext[l], y1 = hext[l + 1];
        out2[i] = make_float2(w.x * y0.x + w.y * y1.x,
                              w.x * y0.y + w.y * y1.y);
    }
}

extern "C" void kernel_launch(void* const* d_in, const int* in_sizes, int n_in,
                              void* d_out, int out_size, void* d_ws, size_t ws_size,
                              hipStream_t stream) {
    const float* LS     = (const float*)d_in[0];
    const float* pilot  = (const float*)d_in[1];
    const float* decayp = (const float*)d_in[2];

    const int NP   = in_sizes[1];
    const int B    = in_sizes[0] / (2 * NP);
    const int Nfft = out_size / (2 * B);

    float4* wts = (float4*)d_ws;

    dai_weights_kernel<<<(Nfft + 255) / 256, 256, 0, stream>>>(
        pilot, decayp, wts, NP, Nfft);

    if (NP == NP_C && Nfft == NFFT_C && (B % ROWS_C) == 0) {
        dai_interp_mr<<<B / ROWS_C, THREADS, 0, stream>>>(
            LS, pilot, wts, (float*)d_out);
    } else {
        dai_interp_generic<<<B, 256, (NP + 2) * sizeof(float2), stream>>>(
            LS, pilot, wts, (float*)d_out, NP, Nfft);
    }
}